// Round 6
// baseline (1981.401 us; speedup 1.0000x reference)
//
#include <hip/hip_runtime.h>

#define NN 8192      // nodes
#define FI 512       // in features
#define FH 512       // hidden features
#define NB 1024      // persistent grid: 4 blocks/CU on 256 CUs
#define NT 256

typedef __attribute__((ext_vector_type(8))) short short8;
typedef __attribute__((ext_vector_type(4))) float f32x4;

__device__ __forceinline__ unsigned short f2bf(float f) {
    unsigned u = __float_as_uint(f);
    unsigned r = (u + 0x7fff + ((u >> 16) & 1)) >> 16;   // RNE
    return (unsigned short)r;
}
__device__ __forceinline__ float bf2f(unsigned short us) {
    return __uint_as_float((unsigned)us << 16);
}

#define GLOAD_LDS16(g, l)                                                        \
    __builtin_amdgcn_global_load_lds((__attribute__((address_space(1))) const void*)(g), \
                                     (__attribute__((address_space(3))) void*)(l), 16, 0, 0)

// ---------------- init barrier state (d_ws is poisoned 0xAA once) ----------------
__global__ void k_init(int* __restrict__ bar) {
    if (threadIdx.x < 2) bar[threadIdx.x] = 0;
}

// ---------------- device-scope grid barrier (all NB blocks co-resident) ----------
__device__ __forceinline__ void gbar(int* __restrict__ bar) {
    __syncthreads();
    if (threadIdx.x == 0) {
        __threadfence();   // release all prior writes device-wide
        int gen = __hip_atomic_load(&bar[1], __ATOMIC_RELAXED, __HIP_MEMORY_SCOPE_AGENT);
        int t = __hip_atomic_fetch_add(&bar[0], 1, __ATOMIC_ACQ_REL, __HIP_MEMORY_SCOPE_AGENT);
        if (t == NB - 1) {
            __hip_atomic_store(&bar[0], 0, __ATOMIC_RELAXED, __HIP_MEMORY_SCOPE_AGENT);
            __hip_atomic_fetch_add(&bar[1], 1, __ATOMIC_RELEASE, __HIP_MEMORY_SCOPE_AGENT);
        } else {
            while (__hip_atomic_load(&bar[1], __ATOMIC_ACQUIRE, __HIP_MEMORY_SCOPE_AGENT) == gen)
                __builtin_amdgcn_s_sleep(4);
        }
        __threadfence();   // acquire: no stale reads after barrier
    }
    __syncthreads();
}

// ---- aggregation helper: one feature-quarter-strip (lane owns 4 feats) ----
__device__ __forceinline__ float agg_pass(const unsigned short* __restrict__ h1,
                                          const int2* __restrict__ csr,
                                          const float* __restrict__ b1,
                                          const float* __restrict__ W2,
                                          int p0, int p1, int fbase, int lane) {
    float a0 = 0.f, a1 = 0.f, a2 = 0.f, a3 = 0.f;
    for (int base = p0; base < p1; base += 64) {
        int cnt = p1 - base; if (cnt > 64) cnt = 64;
        int2 sw = (lane < cnt) ? csr[base + lane] : make_int2(0, 0);
        int j = 0;
        for (; j + 4 <= cnt; j += 4) {
            int   s0 = __shfl(sw.x, j),     s1 = __shfl(sw.x, j + 1);
            int   s2 = __shfl(sw.x, j + 2), s3 = __shfl(sw.x, j + 3);
            float w0 = __int_as_float(__shfl(sw.y, j));
            float w1 = __int_as_float(__shfl(sw.y, j + 1));
            float w2 = __int_as_float(__shfl(sw.y, j + 2));
            float w3 = __int_as_float(__shfl(sw.y, j + 3));
            short4 h0 = *reinterpret_cast<const short4*>(h1 + (size_t)s0 * FH + fbase);
            short4 h1v = *reinterpret_cast<const short4*>(h1 + (size_t)s1 * FH + fbase);
            short4 h2v = *reinterpret_cast<const short4*>(h1 + (size_t)s2 * FH + fbase);
            short4 h3v = *reinterpret_cast<const short4*>(h1 + (size_t)s3 * FH + fbase);
            a0 += w0 * bf2f((unsigned short)h0.x); a1 += w0 * bf2f((unsigned short)h0.y);
            a2 += w0 * bf2f((unsigned short)h0.z); a3 += w0 * bf2f((unsigned short)h0.w);
            a0 += w1 * bf2f((unsigned short)h1v.x); a1 += w1 * bf2f((unsigned short)h1v.y);
            a2 += w1 * bf2f((unsigned short)h1v.z); a3 += w1 * bf2f((unsigned short)h1v.w);
            a0 += w2 * bf2f((unsigned short)h2v.x); a1 += w2 * bf2f((unsigned short)h2v.y);
            a2 += w2 * bf2f((unsigned short)h2v.z); a3 += w2 * bf2f((unsigned short)h2v.w);
            a0 += w3 * bf2f((unsigned short)h3v.x); a1 += w3 * bf2f((unsigned short)h3v.y);
            a2 += w3 * bf2f((unsigned short)h3v.z); a3 += w3 * bf2f((unsigned short)h3v.w);
        }
        for (; j < cnt; ++j) {
            int   sj = __shfl(sw.x, j);
            float wj = __int_as_float(__shfl(sw.y, j));
            short4 hv = *reinterpret_cast<const short4*>(h1 + (size_t)sj * FH + fbase);
            a0 += wj * bf2f((unsigned short)hv.x); a1 += wj * bf2f((unsigned short)hv.y);
            a2 += wj * bf2f((unsigned short)hv.z); a3 += wj * bf2f((unsigned short)hv.w);
        }
    }
    float4 bb = *reinterpret_cast<const float4*>(b1 + fbase);
    float4 ww = *reinterpret_cast<const float4*>(W2 + fbase);
    return fmaxf(a0 + bb.x, 0.f) * ww.x + fmaxf(a1 + bb.y, 0.f) * ww.y
         + fmaxf(a2 + bb.z, 0.f) * ww.z + fmaxf(a3 + bb.w, 0.f) * ww.w;
}

// =============== persistent mega-kernel: all phases, grid barriers ===============
__global__ __launch_bounds__(NT, 4) void k_mega(
        const float* __restrict__ x, const float* __restrict__ o,
        const int* __restrict__ srcE, const int* __restrict__ dstE, int E,
        const float* __restrict__ W1, const float* __restrict__ b1,
        const float* __restrict__ W2, const float* __restrict__ b2,
        const float* __restrict__ Wl, const float* __restrict__ bl,
        int* __restrict__ bar, int* __restrict__ deg, float* __restrict__ dinv,
        int* __restrict__ row_ptr, int* __restrict__ cursor, int2* __restrict__ csr,
        unsigned short* __restrict__ xb, unsigned short* __restrict__ W1t,
        unsigned short* __restrict__ h1, float* __restrict__ z,
        float* __restrict__ h2, float* __restrict__ ohe, float4* __restrict__ out) {
    __shared__ __align__(16) union {
        struct { unsigned short A[64 * 64]; unsigned short B[64 * 64]; } g;  // 16 KB
        float tile[64][65];                                                   // 16.64 KB
        int scan[NT];
    } sm;
    int bid = blockIdx.x, tid = threadIdx.x;
    int lane = tid & 63, wave = tid >> 6;

    // ---- P0: x->bf16 (all blocks); W1 transpose (blk 0-63); zero deg/cursor (64-127)
    #pragma unroll
    for (int u = 0; u < 4; ++u) {
        int i = (bid * 4 + u) * NT + tid;               // 1,048,576 float4 units
        float4 v = reinterpret_cast<const float4*>(x)[i];
        ushort4 h;
        h.x = f2bf(v.x); h.y = f2bf(v.y); h.z = f2bf(v.z); h.w = f2bf(v.w);
        reinterpret_cast<ushort4*>(xb)[i] = h;
    }
    if (bid < 64) {
        int bi = bid >> 3, bj = bid & 7;
        int c = tid & 63, r0 = tid >> 6;
        #pragma unroll
        for (int rr = 0; rr < 16; ++rr) {
            int row = rr * 4 + r0;
            sm.tile[row][c] = W1[(size_t)(bi * 64 + row) * FH + bj * 64 + c];
        }
        __syncthreads();
        #pragma unroll
        for (int rr = 0; rr < 16; ++rr) {
            int row = rr * 4 + r0;
            W1t[(size_t)(bj * 64 + row) * FI + bi * 64 + c] = f2bf(sm.tile[c][row]);
        }
    } else if (bid < 128) {
        int i = (bid - 64) * NT + tid;                  // 16384 ints
        if (i < NN) deg[i] = 0; else cursor[i - NN] = 0;
    }
    gbar(bar);

    // ---- P1: degree count
    for (int i = bid * NT + tid; i < E; i += NB * NT)
        atomicAdd(&deg[dstE[i]], 1);
    gbar(bar);

    // ---- P2: prefix scan (block 0 only) + dinv
    if (bid == 0) {
        int base = tid * 32;
        int s = 0;
        for (int u = 0; u < 32; ++u) {
            int l = deg[base + u] + 1;                  // +1 self loop
            dinv[base + u] = rsqrtf((float)l);
            s += l;
        }
        sm.scan[tid] = s;
        __syncthreads();
        for (int off = 1; off < NT; off <<= 1) {
            int add = (tid >= off) ? sm.scan[tid - off] : 0;
            __syncthreads();
            sm.scan[tid] += add;
            __syncthreads();
        }
        int run = sm.scan[tid] - s;                     // exclusive prefix
        for (int u = 0; u < 32; ++u) {
            row_ptr[base + u] = run;
            run += deg[base + u] + 1;
        }
        if (tid == NT - 1) row_ptr[NN] = sm.scan[NT - 1];
    }
    gbar(bar);

    // ---- P3: CSR fill (edges + self loops)
    for (int i = bid * NT + tid; i < E + NN; i += NB * NT) {
        if (i < E) {
            int s = srcE[i], d = dstE[i];
            int p = row_ptr[d] + atomicAdd(&cursor[d], 1);
            csr[p] = make_int2(s, __float_as_int(dinv[s] * dinv[d]));
        } else {
            int v = i - E;
            int p = row_ptr[v] + atomicAdd(&cursor[v], 1);
            csr[p] = make_int2(v, __float_as_int(dinv[v] * dinv[v]));
        }
    }
    gbar(bar);

    // ---- P4: bf16 MFMA GEMM, BM=BN=BK=64; block -> (bm = bid>>3, bn = bid&7)
    {
        int wm = wave >> 1, wn = wave & 1;
        int bm = (bid >> 3) * 64, bn = (bid & 7) * 64;
        f32x4 acc[2][2] = {};
        int r  = lane & 15;
        int s0 = lane >> 4;
        for (int kt = 0; kt < FI / 64; ++kt) {
            #pragma unroll
            for (int t = 0; t < 2; ++t) {
                int q   = t * NT + tid;
                int row = q >> 3;
                int sl  = q & 7;
                int sg  = sl ^ (row & 7);
                GLOAD_LDS16(xb  + (size_t)(bm + row) * FI + kt * 64 + sg * 8, sm.g.A + q * 8);
                GLOAD_LDS16(W1t + (size_t)(bn + row) * FI + kt * 64 + sg * 8, sm.g.B + q * 8);
            }
            __syncthreads();
            #pragma unroll
            for (int kc = 0; kc < 2; ++kc) {
                short8 a[2], b[2];
                #pragma unroll
                for (int m = 0; m < 2; ++m) {
                    int row = wm * 32 + m * 16 + r;
                    int sl  = (kc * 4 + s0) ^ (row & 7);
                    a[m] = *reinterpret_cast<const short8*>(sm.g.A + row * 64 + sl * 8);
                }
                #pragma unroll
                for (int n = 0; n < 2; ++n) {
                    int row = wn * 32 + n * 16 + r;
                    int sl  = (kc * 4 + s0) ^ (row & 7);
                    b[n] = *reinterpret_cast<const short8*>(sm.g.B + row * 64 + sl * 8);
                }
                #pragma unroll
                for (int m = 0; m < 2; ++m)
                    #pragma unroll
                    for (int n = 0; n < 2; ++n)
                        acc[m][n] = __builtin_amdgcn_mfma_f32_16x16x32_bf16(a[m], b[n], acc[m][n], 0, 0, 0);
            }
            __syncthreads();
        }
        #pragma unroll
        for (int m = 0; m < 2; ++m)
            #pragma unroll
            for (int n = 0; n < 2; ++n) {
                int col = bn + wn * 32 + n * 16 + (lane & 15);
                int rw0 = bm + wm * 32 + m * 16 + (lane >> 4) * 4;
                #pragma unroll
                for (int reg = 0; reg < 4; ++reg)
                    h1[(size_t)(rw0 + reg) * FH + col] = f2bf(acc[m][n][reg]);
            }
    }
    gbar(bar);

    // ---- P5/P6: aggregation in two feature-half passes (4 MB L2-resident each)
    {
        int gw = bid * 4 + wave;                 // 0..4095; 2 nodes per wave
        int v0 = gw * 2, v1 = gw * 2 + 1;
        int a0 = row_ptr[v0], a1 = row_ptr[v0 + 1], a2 = row_ptr[v1 + 1];
        float vp0, vp1;
        // pass 0: feats [0,256)
        vp0 = agg_pass(h1, csr, b1, W2, a0, a1, 0 * 256 + lane * 4, lane);
        vp1 = agg_pass(h1, csr, b1, W2, a1, a2, 0 * 256 + lane * 4, lane);
        gbar(bar);
        // pass 1: feats [256,512)
        vp0 += agg_pass(h1, csr, b1, W2, a0, a1, 1 * 256 + lane * 4, lane);
        vp1 += agg_pass(h1, csr, b1, W2, a1, a2, 1 * 256 + lane * 4, lane);
        #pragma unroll
        for (int off = 32; off; off >>= 1) {
            vp0 += __shfl_down(vp0, off);
            vp1 += __shfl_down(vp1, off);
        }
        if (lane == 0) { z[v0] = vp0; z[v1] = vp1; }
    }
    gbar(bar);

    // ---- P7: layer-2 aggregation (scalar) + ohe
    {
        int v = bid * NT + tid;
        if (v < NN) {
            float acc = 0.f;
            int p1 = row_ptr[v + 1];
            for (int p = row_ptr[v]; p < p1; ++p) {
                int2 sw = csr[p];
                acc += __int_as_float(sw.y) * z[sw.x];
            }
            h2[v] = acc + b2[0];
            float4 ov = *reinterpret_cast<const float4*>(&o[(size_t)v * 4]);
            ohe[v] = ov.x * Wl[0] + ov.y * Wl[1] + ov.z * Wl[2] + ov.w * Wl[3] + bl[0];
        }
    }
    gbar(bar);

    // ---- P8: out[i][j] = h2[j] + ohe[i]; 8 rows per block
    {
        float4 h[8];
        #pragma unroll
        for (int u = 0; u < 8; ++u) h[u] = reinterpret_cast<const float4*>(h2)[u * NT + tid];
        int i0 = bid * 8;
        #pragma unroll
        for (int rr = 0; rr < 8; ++rr) {
            float oi = ohe[i0 + rr];
            float4* dst = out + (size_t)(i0 + rr) * 2048;
            #pragma unroll
            for (int u = 0; u < 8; ++u) {
                float4 v = h[u];
                dst[u * NT + tid] = make_float4(v.x + oi, v.y + oi, v.z + oi, v.w + oi);
            }
        }
    }
}

extern "C" void kernel_launch(void* const* d_in, const int* in_sizes, int n_in,
                              void* d_out, int out_size, void* d_ws, size_t ws_size,
                              hipStream_t stream) {
    const float* x  = (const float*)d_in[0];
    const float* o  = (const float*)d_in[1];
    const int*   ei = (const int*)d_in[2];
    const float* W1 = (const float*)d_in[3];
    const float* b1 = (const float*)d_in[4];
    const float* W2 = (const float*)d_in[5];
    const float* b2 = (const float*)d_in[6];
    const float* Wl = (const float*)d_in[7];
    const float* bl = (const float*)d_in[8];
    float* out = (float*)d_out;

    const int E = in_sizes[2] / 2;
    const int* src = ei;
    const int* dst = ei + E;

    // workspace carve-up (256B aligned)
    char* p = (char*)d_ws;
    auto alloc = [&](size_t bytes) {
        char* r = p;
        p += (bytes + 255) & ~(size_t)255;
        return r;
    };
    int*   bar     = (int*)  alloc(2 * 4);
    int*   deg     = (int*)  alloc(NN * 4);
    float* dinv    = (float*)alloc(NN * 4);
    int*   row_ptr = (int*)  alloc((NN + 1) * 4);
    int*   cursor  = (int*)  alloc(NN * 4);
    int2*  csr     = (int2*) alloc((size_t)(E + NN) * 8);
    unsigned short* xb  = (unsigned short*)alloc((size_t)NN * FI * 2);
    unsigned short* W1t = (unsigned short*)alloc((size_t)FH * FI * 2);
    unsigned short* h1  = (unsigned short*)alloc((size_t)NN * FH * 2);
    float* z       = (float*)alloc(NN * 4);
    float* h2      = (float*)alloc(NN * 4);
    float* ohe     = (float*)alloc(NN * 4);

    k_init<<<1, 64, 0, stream>>>(bar);
    k_mega<<<NB, NT, 0, stream>>>(x, o, src, dst, E, W1, b1, W2, b2, Wl, bl,
                                  bar, deg, dinv, row_ptr, cursor, csr,
                                  xb, W1t, h1, z, h2, ohe, (float4*)out);
}

// Round 7
// 143.440 us; speedup vs baseline: 13.8135x; 13.8135x over previous
//
#include <hip/hip_runtime.h>

#define NN 8192      // nodes
#define FI 512       // in features
#define FH 512       // hidden features

typedef __attribute__((ext_vector_type(8))) short short8;
typedef __attribute__((ext_vector_type(4))) float f32x4;

__device__ __forceinline__ unsigned short f2bf(float f) {
    unsigned u = __float_as_uint(f);
    unsigned r = (u + 0x7fff + ((u >> 16) & 1)) >> 16;   // RNE
    return (unsigned short)r;
}
__device__ __forceinline__ float bf2f(unsigned short us) {
    return __uint_as_float((unsigned)us << 16);
}

#define GLOAD_LDS16(g, l)                                                        \
    __builtin_amdgcn_global_load_lds((__attribute__((address_space(1))) const void*)(g), \
                                     (__attribute__((address_space(3))) void*)(l), 16, 0, 0)

// ------- fused prep:
//   blocks 0..1023    : cvt x -> bf16, grid-stride (4 float4 per thread)
//   blocks 1024..1087 : W1 transpose -> bf16 via padded LDS tile
//   blocks 1088..1119 : zero deg/cursor
__global__ __launch_bounds__(256) void k_prep(const float* __restrict__ x,
                                              const float* __restrict__ W1,
                                              unsigned short* __restrict__ xb,
                                              unsigned short* __restrict__ W1t,
                                              int* __restrict__ deg,
                                              int* __restrict__ cursor) {
    int b = blockIdx.x, t = threadIdx.x;
    if (b < 1024) {
        #pragma unroll
        for (int u = 0; u < 4; ++u) {
            int i = (b * 4 + u) * 256 + t;           // 1M float4 units total
            float4 v = reinterpret_cast<const float4*>(x)[i];
            ushort4 h;
            h.x = f2bf(v.x); h.y = f2bf(v.y); h.z = f2bf(v.z); h.w = f2bf(v.w);
            reinterpret_cast<ushort4*>(xb)[i] = h;
        }
    } else if (b < 1088) {
        __shared__ float tile[64][65];
        int bi = (b - 1024) >> 3;                    // k-tile
        int bj = (b - 1024) & 7;                     // n-tile
        int c = t & 63, r0 = t >> 6;                 // 4 rows per pass
        #pragma unroll
        for (int rr = 0; rr < 16; ++rr) {
            int row = rr * 4 + r0;
            tile[row][c] = W1[(size_t)(bi * 64 + row) * FH + bj * 64 + c];
        }
        __syncthreads();
        #pragma unroll
        for (int rr = 0; rr < 16; ++rr) {
            int row = rr * 4 + r0;                   // n within tile
            W1t[(size_t)(bj * 64 + row) * FI + bi * 64 + c] = f2bf(tile[c][row]);
        }
    } else {
        int i = (b - 1088) * 256 + t;
        deg[i] = 0; cursor[i] = 0;
    }
}

// ---------------- degree count ----------------
__global__ void k_deg(const int* __restrict__ dst, int E, int* __restrict__ deg) {
    int i = blockIdx.x * blockDim.x + threadIdx.x;
    if (i < E) atomicAdd(&deg[dst[i]], 1);
}

// ---------------- prefix scan over row lengths (deg+1) + dinv ----------------
__global__ __launch_bounds__(1024) void k_scan(const int* __restrict__ deg,
                                               int* __restrict__ row_ptr,
                                               float* __restrict__ dinv) {
    __shared__ int lds[1024];
    int tid = threadIdx.x;
    int base = tid * 8;
    int l[8]; int s = 0;
    #pragma unroll
    for (int u = 0; u < 8; ++u) {
        l[u] = deg[base + u] + 1;                       // +1 self loop
        dinv[base + u] = rsqrtf((float)l[u]);
        s += l[u];
    }
    lds[tid] = s;
    __syncthreads();
    for (int off = 1; off < 1024; off <<= 1) {
        int add = (tid >= off) ? lds[tid - off] : 0;
        __syncthreads();
        lds[tid] += add;
        __syncthreads();
    }
    int run = lds[tid] - s;  // exclusive prefix
    #pragma unroll
    for (int u = 0; u < 8; ++u) { row_ptr[base + u] = run; run += l[u]; }
    if (tid == 1023) row_ptr[NN] = lds[1023];
}

// ---------------- CSR fill: packed (src, weight-bits) pairs ----------------
__global__ void k_fill(const int* __restrict__ src, const int* __restrict__ dst, int E,
                       const float* __restrict__ dinv, const int* __restrict__ row_ptr,
                       int* __restrict__ cursor, int2* __restrict__ csr) {
    int i = blockIdx.x * blockDim.x + threadIdx.x;
    if (i < E) {
        int s = src[i], d = dst[i];
        int p = row_ptr[d] + atomicAdd(&cursor[d], 1);
        csr[p] = make_int2(s, __float_as_int(dinv[s] * dinv[d]));
    } else if (i < E + NN) {
        int v = i - E;
        int p = row_ptr[v] + atomicAdd(&cursor[v], 1);
        csr[p] = make_int2(v, __float_as_int(dinv[v] * dinv[v]));
    }
}

// -------- bf16 MFMA GEMM: h1 = xb @ W1t^T; BM=BN=BK=64; epilogue -> fp8 e4m3 -----
__global__ __launch_bounds__(256) void k_gemm(const unsigned short* __restrict__ xb,
                                              const unsigned short* __restrict__ W1t,
                                              unsigned char* __restrict__ h8) {
    __shared__ __align__(16) unsigned short As[64 * 64];
    __shared__ __align__(16) unsigned short Bs[64 * 64];
    int tid  = threadIdx.x;
    int lane = tid & 63;
    int wave = tid >> 6;
    int wm = wave >> 1, wn = wave & 1;           // 2x2 wave grid, 32x32 per wave
    int bm = blockIdx.y * 64, bn = blockIdx.x * 64;

    f32x4 acc[2][2] = {};

    int r  = lane & 15;       // fragment row within 16
    int s0 = lane >> 4;       // 16B k-slot 0..3 (within a 32-k chunk)

    for (int kt = 0; kt < FI / 64; ++kt) {
        // stage 64x64 bf16 tiles: 512 16B-units each, 2 per thread
        #pragma unroll
        for (int t = 0; t < 2; ++t) {
            int q   = t * 256 + tid;
            int row = q >> 3;                     // 8 slots per row
            int sl  = q & 7;
            int sg  = sl ^ (row & 7);             // pre-swizzled source slot
            GLOAD_LDS16(xb  + (size_t)(bm + row) * FI + kt * 64 + sg * 8, As + q * 8);
            GLOAD_LDS16(W1t + (size_t)(bn + row) * FI + kt * 64 + sg * 8, Bs + q * 8);
        }
        __syncthreads();

        #pragma unroll
        for (int kc = 0; kc < 2; ++kc) {          // two k=32 chunks, ascending k order
            short8 a[2], b[2];
            #pragma unroll
            for (int m = 0; m < 2; ++m) {
                int row = wm * 32 + m * 16 + r;
                int sl  = (kc * 4 + s0) ^ (row & 7);
                a[m] = *reinterpret_cast<const short8*>(As + row * 64 + sl * 8);
            }
            #pragma unroll
            for (int n = 0; n < 2; ++n) {
                int row = wn * 32 + n * 16 + r;
                int sl  = (kc * 4 + s0) ^ (row & 7);
                b[n] = *reinterpret_cast<const short8*>(Bs + row * 64 + sl * 8);
            }
            #pragma unroll
            for (int m = 0; m < 2; ++m)
                #pragma unroll
                for (int n = 0; n < 2; ++n)
                    acc[m][n] = __builtin_amdgcn_mfma_f32_16x16x32_bf16(a[m], b[n], acc[m][n], 0, 0, 0);
        }
        __syncthreads();
    }

    // C/D layout: col = lane&15, row = (lane>>4)*4 + reg  [m89-verified]
    #pragma unroll
    for (int m = 0; m < 2; ++m) {
        #pragma unroll
        for (int n = 0; n < 2; ++n) {
            int col = bn + wn * 32 + n * 16 + (lane & 15);
            int rw0 = bm + wm * 32 + m * 16 + (lane >> 4) * 4;
            #pragma unroll
            for (int reg = 0; reg < 4; ++reg) {
                float v = acc[m][n][reg];
                int pk = __builtin_amdgcn_cvt_pk_fp8_f32(v, v, 0, false);
                h8[(size_t)(rw0 + reg) * FH + col] = (unsigned char)(pk & 0xff);
            }
        }
    }
}

// ---- fp8x8 accumulate helper ----
__device__ __forceinline__ void acc8(float* __restrict__ acc, uint2 rv, float w) {
    acc[0] += w * __builtin_amdgcn_cvt_f32_fp8((int)rv.x, 0);
    acc[1] += w * __builtin_amdgcn_cvt_f32_fp8((int)rv.x, 1);
    acc[2] += w * __builtin_amdgcn_cvt_f32_fp8((int)rv.x, 2);
    acc[3] += w * __builtin_amdgcn_cvt_f32_fp8((int)rv.x, 3);
    acc[4] += w * __builtin_amdgcn_cvt_f32_fp8((int)rv.y, 0);
    acc[5] += w * __builtin_amdgcn_cvt_f32_fp8((int)rv.y, 1);
    acc[6] += w * __builtin_amdgcn_cvt_f32_fp8((int)rv.y, 2);
    acc[7] += w * __builtin_amdgcn_cvt_f32_fp8((int)rv.y, 3);
}

// ------- fused: agg1[v] = relu(sum w*h8[src] + b1); z[v] = dot(agg1[v], W2) -------
// one wave per node; lane owns feats [lane*8, lane*8+8); fp8 row = 512B, L2-resident
__global__ __launch_bounds__(256) void k_agg(const unsigned char* __restrict__ h8,
                                             const int* __restrict__ row_ptr,
                                             const int2* __restrict__ csr,
                                             const float* __restrict__ b1,
                                             const float* __restrict__ W2,
                                             float* __restrict__ z) {
    int lane = threadIdx.x & 63;
    int v = blockIdx.x * 4 + (threadIdx.x >> 6);
    float acc[8] = {};
    int p0 = row_ptr[v], p1 = row_ptr[v + 1];
    for (int base = p0; base < p1; base += 64) {
        int cnt = p1 - base; if (cnt > 64) cnt = 64;
        int2 sw = (lane < cnt) ? csr[base + lane] : make_int2(0, 0);
        int j = 0;
        for (; j + 4 <= cnt; j += 4) {
            int   s0 = __shfl(sw.x, j),     s1 = __shfl(sw.x, j + 1);
            int   s2 = __shfl(sw.x, j + 2), s3 = __shfl(sw.x, j + 3);
            float w0 = __int_as_float(__shfl(sw.y, j));
            float w1 = __int_as_float(__shfl(sw.y, j + 1));
            float w2 = __int_as_float(__shfl(sw.y, j + 2));
            float w3 = __int_as_float(__shfl(sw.y, j + 3));
            uint2 r0 = *reinterpret_cast<const uint2*>(h8 + (size_t)s0 * FH + lane * 8);
            uint2 r1 = *reinterpret_cast<const uint2*>(h8 + (size_t)s1 * FH + lane * 8);
            uint2 r2 = *reinterpret_cast<const uint2*>(h8 + (size_t)s2 * FH + lane * 8);
            uint2 r3 = *reinterpret_cast<const uint2*>(h8 + (size_t)s3 * FH + lane * 8);
            acc8(acc, r0, w0);
            acc8(acc, r1, w1);
            acc8(acc, r2, w2);
            acc8(acc, r3, w3);
        }
        for (; j < cnt; ++j) {
            int   sj = __shfl(sw.x, j);
            float wj = __int_as_float(__shfl(sw.y, j));
            uint2 rj = *reinterpret_cast<const uint2*>(h8 + (size_t)sj * FH + lane * 8);
            acc8(acc, rj, wj);
        }
    }
    const float4* b4 = reinterpret_cast<const float4*>(b1 + lane * 8);
    const float4* w4 = reinterpret_cast<const float4*>(W2 + lane * 8);
    float4 b0 = b4[0], bs1 = b4[1];
    float4 w0 = w4[0], ws1 = w4[1];
    float val = fmaxf(acc[0] + b0.x, 0.f) * w0.x + fmaxf(acc[1] + b0.y, 0.f) * w0.y
              + fmaxf(acc[2] + b0.z, 0.f) * w0.z + fmaxf(acc[3] + b0.w, 0.f) * w0.w
              + fmaxf(acc[4] + bs1.x, 0.f) * ws1.x + fmaxf(acc[5] + bs1.y, 0.f) * ws1.y
              + fmaxf(acc[6] + bs1.z, 0.f) * ws1.z + fmaxf(acc[7] + bs1.w, 0.f) * ws1.w;
    #pragma unroll
    for (int off = 32; off; off >>= 1) val += __shfl_down(val, off);
    if (lane == 0) z[v] = val;
}

// ---------------- aggregation 2 (scalar) + ohe ----------------
__global__ void k_node(const float* __restrict__ z,
                       const int* __restrict__ row_ptr,
                       const int2* __restrict__ csr,
                       const float* __restrict__ b2,
                       const float* __restrict__ o,
                       const float* __restrict__ Wl,
                       const float* __restrict__ bl,
                       float* __restrict__ h2, float* __restrict__ ohe) {
    int v = blockIdx.x * blockDim.x + threadIdx.x;
    if (v >= NN) return;
    float acc = 0.f;
    int p1 = row_ptr[v + 1];
    for (int p = row_ptr[v]; p < p1; ++p) {
        int2 sw = csr[p];
        acc += __int_as_float(sw.y) * z[sw.x];
    }
    h2[v] = acc + b2[0];
    float4 ov = *reinterpret_cast<const float4*>(&o[(size_t)v * 4]);
    ohe[v] = ov.x * Wl[0] + ov.y * Wl[1] + ov.z * Wl[2] + ov.w * Wl[3] + bl[0];
}

// -------- out[i][j] = h2[j] + ohe[i]; 2048 blocks, 4 rows/block, h2 row in regs ----
__global__ __launch_bounds__(256) void k_out(const float* __restrict__ h2,
                                             const float* __restrict__ ohe,
                                             float4* __restrict__ out) {
    int i0 = blockIdx.x * 4;
    int t  = threadIdx.x;
    float4 h[8];
    #pragma unroll
    for (int u = 0; u < 8; ++u) h[u] = reinterpret_cast<const float4*>(h2)[u * 256 + t];
    #pragma unroll
    for (int rr = 0; rr < 4; ++rr) {
        float oi = ohe[i0 + rr];
        float4* dst = out + (size_t)(i0 + rr) * 2048;
        #pragma unroll
        for (int u = 0; u < 8; ++u) {
            float4 v = h[u];
            dst[u * 256 + t] = make_float4(v.x + oi, v.y + oi, v.z + oi, v.w + oi);
        }
    }
}

extern "C" void kernel_launch(void* const* d_in, const int* in_sizes, int n_in,
                              void* d_out, int out_size, void* d_ws, size_t ws_size,
                              hipStream_t stream) {
    const float* x  = (const float*)d_in[0];
    const float* o  = (const float*)d_in[1];
    const int*   ei = (const int*)d_in[2];
    const float* W1 = (const float*)d_in[3];
    const float* b1 = (const float*)d_in[4];
    const float* W2 = (const float*)d_in[5];
    const float* b2 = (const float*)d_in[6];
    const float* Wl = (const float*)d_in[7];
    const float* bl = (const float*)d_in[8];
    float* out = (float*)d_out;

    const int E = in_sizes[2] / 2;
    const int* src = ei;
    const int* dst = ei + E;

    // workspace carve-up (256B aligned)
    char* p = (char*)d_ws;
    auto alloc = [&](size_t bytes) {
        char* r = p;
        p += (bytes + 255) & ~(size_t)255;
        return r;
    };
    int*   deg     = (int*)  alloc(NN * 4);
    float* dinv    = (float*)alloc(NN * 4);
    int*   row_ptr = (int*)  alloc((NN + 1) * 4);
    int*   cursor  = (int*)  alloc(NN * 4);
    int2*  csr     = (int2*) alloc((size_t)(E + NN) * 8);
    unsigned short* xb  = (unsigned short*)alloc((size_t)NN * FI * 2);
    unsigned short* W1t = (unsigned short*)alloc((size_t)FH * FI * 2);
    unsigned char*  h8  = (unsigned char*) alloc((size_t)NN * FH);
    float* z       = (float*)alloc(NN * 4);
    float* h2      = (float*)alloc(NN * 4);
    float* ohe     = (float*)alloc(NN * 4);

    k_prep <<<1120, 256, 0, stream>>>(x, W1, xb, W1t, deg, cursor);
    k_deg  <<<(E + 255) / 256, 256, 0, stream>>>(dst, E, deg);
    k_scan <<<1, 1024, 0, stream>>>(deg, row_ptr, dinv);
    k_fill <<<(E + NN + 255) / 256, 256, 0, stream>>>(src, dst, E, dinv, row_ptr, cursor, csr);
    k_gemm <<<dim3(FH / 64, NN / 64), 256, 0, stream>>>(xb, W1t, h8);
    k_agg  <<<NN / 4, 256, 0, stream>>>(h8, row_ptr, csr, b1, W2, z);
    k_node <<<(NN + 255) / 256, 256, 0, stream>>>(z, row_ptr, csr, b2, o, Wl, bl, h2, ohe);
    k_out  <<<NN / 4, 256, 0, stream>>>(h2, ohe, (float4*)out);
}